// Round 13
// baseline (316.045 us; speedup 1.0000x reference)
//
#include <hip/hip_runtime.h>
#include <hip/hip_bf16.h>

// CrossAttention R19 = R14 pipeline + attn av-hoist + setprio (proj reverted).
//  - R18 post-mortem: 8-wave proj neutral AND violated the LDS-side ratio rule
//    (8 MFMA : 6 ds_read vs 16:8). Reverted proj to R14's 256-thread mode-2.
//  - attn fix: the P-write->bp-read compiler fence ALSO pinned the av (V-frag)
//    reads below it -- 8 ds_read_b128 serialized on the post-fence critical
//    path each iter. V-plane was published at the PREVIOUS barrier and doesn't
//    alias P => hoist av reads to iteration start (overlap with QK+exp2).
//  - attn: s_setprio(1) around the PV MFMA cluster (T5; phase-diverse 16
//    waves/CU from 2-block residency + role-split staging).
//  - qkv: R14 3-buf counted (proven). attn structure otherwise R14.

typedef short bf16x8 __attribute__((ext_vector_type(8)));
typedef float f32x4 __attribute__((ext_vector_type(4)));

__device__ __forceinline__ short f2s(float f) {
    __hip_bfloat16 h = __float2bfloat16(f);
    return __builtin_bit_cast(short, h);
}

__device__ __forceinline__ f32x4 mfma16(bf16x8 a, bf16x8 b, f32x4 c) {
    return __builtin_amdgcn_mfma_f32_16x16x32_bf16(a, b, c, 0, 0, 0);
}

__device__ __forceinline__ void gload16(short* lds, const short* g) {
    __builtin_amdgcn_global_load_lds((const __attribute__((address_space(1))) void*)g,
                                     (__attribute__((address_space(3))) void*)lds,
                                     16, 0, 0);
}

// Barrier with guaranteed counter drain (correctness of single-barrier dbuf).
__device__ __forceinline__ void drain_barrier() {
    asm volatile("s_waitcnt vmcnt(0) lgkmcnt(0)" ::: "memory");
    __syncthreads();
}

__device__ __forceinline__ unsigned int fbits(float f) {
    return __builtin_bit_cast(unsigned int, f);
}

// ---------------- prep: fp32 -> bf16 for activations ----------------
__global__ __launch_bounds__(256) void conv_to_bf16(const float* __restrict__ x,
                                                    const float* __restrict__ ctx,
                                                    short* __restrict__ xb,
                                                    short* __restrict__ cb) {
    const size_t NV = 2097152;
    size_t i = (size_t)blockIdx.x * 256 + threadIdx.x;
    const float4* src = (i < NV) ? (const float4*)x : (const float4*)ctx;
    short* dst = (i < NV) ? xb : cb;
    size_t idx = (i < NV) ? i : i - NV;
    float4 v = src[idx];
    short4 o;
    o.x = f2s(v.x); o.y = f2s(v.y); o.z = f2s(v.z); o.w = f2s(v.w);
    ((short4*)dst)[idx] = o;
}

// ---------------- prep: W -> W^T bf16 (K+V halves contiguous in WkvT) ----------------
__global__ __launch_bounds__(256) void transpose_weights(
    const float* __restrict__ q_w, const float* __restrict__ kv_w,
    const float* __restrict__ proj_w,
    short* __restrict__ WqT, short* __restrict__ WkvT, short* __restrict__ WpT) {
    __shared__ float t[32][33];
    const float* src; short* dst; int ld, coff;
    switch (blockIdx.z) {
        case 0:  src = q_w;    dst = WqT;                 ld = 1024; coff = 0;    break;
        case 1:  src = kv_w;   dst = WkvT;                ld = 2048; coff = 0;    break;
        case 2:  src = kv_w;   dst = WkvT + 1024 * 1024;  ld = 2048; coff = 1024; break;
        default: src = proj_w; dst = WpT;                 ld = 1024; coff = 0;    break;
    }
    int n0 = blockIdx.x * 32, k0 = blockIdx.y * 32;
    int tx = threadIdx.x & 31, ty = threadIdx.x >> 5;
    #pragma unroll
    for (int j = 0; j < 32; j += 8)
        t[ty + j][tx] = src[(size_t)(k0 + ty + j) * ld + coff + n0 + tx];
    __syncthreads();
    #pragma unroll
    for (int j = 0; j < 32; j += 8)
        dst[(size_t)(n0 + ty + j) * 1024 + k0 + tx] = f2s(t[tx][ty + j]);
}

// ---------------- fused QKV GEMM 128x128, K=1024, 3-buffer counted pipeline ----------------
// grid (64,24): x = m-tile (XCD=m%8). y<8: Q path (LN(qn)+RoPE+scale -> outQ);
// y>=8: KV path (n0=(y-8)*128; n0<1024: LN(kn) -> outK; else V^T -> outV).
__global__ __launch_bounds__(256, 3) void gemm_qkv(
    const short* __restrict__ A,      // xb
    const short* __restrict__ Bt,     // WqT
    const short* __restrict__ A2,     // cb
    const short* __restrict__ Bt2,    // WkvT
    const float* __restrict__ qn_scale, const float* __restrict__ qn_bias,
    const float* __restrict__ kn_scale, const float* __restrict__ kn_bias,
    short* __restrict__ outQ, short* __restrict__ outK, short* __restrict__ outV) {
    __shared__ short smem[24576];
    const int tid = threadIdx.x;
    const int w = tid >> 6, lane = tid & 63, quad = lane >> 4, l15 = lane & 15;
    const int wr = w & 1, wc = w >> 1;
    const int m0 = blockIdx.x * 128;  // x=m (XCD=m%8)

    const int y = blockIdx.y;
    const bool qpath = (y < 8);
    const int n0 = qpath ? y * 128 : (y - 8) * 128;
    const short* Ab = qpath ? A : A2;
    const short* Bb = qpath ? Bt : Bt2;
    const float* lns = qpath ? qn_scale : kn_scale;
    const float* lnb = qpath ? qn_bias : kn_bias;
    const bool vpath = (!qpath) && (n0 >= 1024);

    const int srow = lane >> 2, slot = lane & 3;
    const int kslot = (slot ^ ((srow >> 1) & 3)) * 8;  // XOR swizzle: 2-way banks on read
    const short* Ag0 = Ab + (size_t)(m0 + w * 32 + srow) * 1024 + kslot;
    const short* Ag1 = Ag0 + (size_t)16 * 1024;
    const short* Bg0 = Bb + (size_t)(n0 + w * 32 + srow) * 1024 + kslot;
    const short* Bg1 = Bg0 + (size_t)16 * 1024;
    short* Al = smem + w * 1024;           // + buf*8192
    short* Bl = smem + 4096 + w * 1024;    // + buf*8192

    f32x4 acc[4][4];
    #pragma unroll
    for (int r = 0; r < 4; r++)
        #pragma unroll
        for (int c = 0; c < 4; c++) acc[r][c] = f32x4{0.f, 0.f, 0.f, 0.f};

    const int rsw = (l15 >> 1) & 3;
    const int rch = (quad ^ rsw) * 8;

    // prologue: tile 0 -> buf0, tile 1 -> buf1; wait oldest 4 (tile 0) only.
    gload16(Al,              Ag0);
    gload16(Al + 512,        Ag1);
    gload16(Bl,              Bg0);
    gload16(Bl + 512,        Bg1);
    gload16(Al + 8192,       Ag0 + 32);
    gload16(Al + 8192 + 512, Ag1 + 32);
    gload16(Bl + 8192,       Bg0 + 32);
    gload16(Bl + 8192 + 512, Bg1 + 32);
    asm volatile("s_waitcnt vmcnt(4) lgkmcnt(0)" ::: "memory");
    __builtin_amdgcn_s_barrier();

    int curo = 0;       // current compute buffer offset (shorts)
    int pfo = 16384;    // prefetch target buffer offset (tile t+2)
    #pragma unroll 1
    for (int t = 0; t < 32; t++) {
        if (t < 30) {
            const int k0 = (t + 2) * 32;
            gload16(Al + pfo,       Ag0 + k0);
            gload16(Al + pfo + 512, Ag1 + k0);
            gload16(Bl + pfo,       Bg0 + k0);
            gload16(Bl + pfo + 512, Bg1 + k0);
        }
        bf16x8 af[4], bfr[4];
        #pragma unroll
        for (int rt = 0; rt < 4; rt++)
            af[rt] = *(const bf16x8*)(smem + curo + (wr * 64 + rt * 16 + l15) * 32 + rch);
        #pragma unroll
        for (int ct = 0; ct < 4; ct++)
            bfr[ct] = *(const bf16x8*)(smem + curo + 4096 + (wc * 64 + ct * 16 + l15) * 32 + rch);
        #pragma unroll
        for (int rt = 0; rt < 4; rt++)
            #pragma unroll
            for (int ct = 0; ct < 4; ct++)
                acc[rt][ct] = mfma16(af[rt], bfr[ct], acc[rt][ct]);
        if (t < 30) {
            asm volatile("s_waitcnt vmcnt(4) lgkmcnt(0)" ::: "memory");
        } else {
            asm volatile("s_waitcnt vmcnt(0) lgkmcnt(0)" ::: "memory");
        }
        __builtin_amdgcn_s_barrier();
        curo += 8192; if (curo == 24576) curo = 0;
        pfo  += 8192; if (pfo  == 24576) pfo  = 0;
    }

    // epilogue: lane holds C[row = wr*64+rt*16+quad*4+i][col = wc*64+ct*16+l15]
    if (!vpath) {
        #pragma unroll
        for (int rt = 0; rt < 4; rt++) {
            #pragma unroll
            for (int i = 0; i < 4; i++) {
                float s = acc[rt][0][i] + acc[rt][1][i] + acc[rt][2][i] + acc[rt][3][i];
                float q = acc[rt][0][i] * acc[rt][0][i] + acc[rt][1][i] * acc[rt][1][i] +
                          acc[rt][2][i] * acc[rt][2][i] + acc[rt][3][i] * acc[rt][3][i];
                #pragma unroll
                for (int off = 1; off < 16; off <<= 1) {
                    s += __shfl_xor(s, off, 64);
                    q += __shfl_xor(q, off, 64);
                }
                float mu = s * (1.f / 64.f);
                float var = q * (1.f / 64.f) - mu * mu;
                float rs = rsqrtf(var + 1e-5f);
                float vals[4];
                #pragma unroll
                for (int ct = 0; ct < 4; ct++) {
                    int hd = ct * 16 + l15;
                    vals[ct] = (acc[rt][ct][i] - mu) * rs * lns[hd] + lnb[hd];
                }
                if (qpath) {  // RoPE pairs (hd, hd+32) = (ct, ct+2), then *0.125*log2e
                    int sp = (m0 + wr * 64 + rt * 16 + quad * 4 + i) & 2047;
                    #pragma unroll
                    for (int ct = 0; ct < 2; ct++) {
                        int hd1 = ct * 16 + l15;
                        float ang = (float)sp * exp2f((float)hd1 * (-13.287712379549449f / 32.f));
                        float sn, cs;
                        sincosf(ang, &sn, &cs);
                        float v1 = vals[ct], v2 = vals[ct + 2];
                        vals[ct]     = v1 * cs - v2 * sn;
                        vals[ct + 2] = v1 * sn + v2 * cs;
                    }
                    #pragma unroll
                    for (int ct = 0; ct < 4; ct++) vals[ct] *= 0.1803368801f;
                }
                #pragma unroll
                for (int ct = 0; ct < 4; ct++) acc[rt][ct][i] = vals[ct];
            }
        }
        drain_barrier();
        short* Csm = smem;  // overlay: [128][132] bf16, +4 pad
        #pragma unroll
        for (int rt = 0; rt < 4; rt++)
            #pragma unroll
            for (int ct = 0; ct < 4; ct++)
                #pragma unroll
                for (int i = 0; i < 4; i++)
                    Csm[(wr * 64 + rt * 16 + quad * 4 + i) * 132 + wc * 64 + ct * 16 + l15] =
                        f2s(acc[rt][ct][i]);
        drain_barrier();
        short* dst = qpath ? outQ : outK;
        #pragma unroll
        for (int it = 0; it < 8; it++) {
            int row = it * 16 + (tid >> 4);
            int chunk = tid & 15;
            bf16x8 v = *(const bf16x8*)(Csm + row * 132 + chunk * 8);
            int hh = ((n0 & 1023) >> 6) + (chunk >> 3);
            int m = m0 + row, b = m >> 11, sp = m & 2047;
            *(bf16x8*)(dst + ((size_t)(b * 16 + hh) * 2048 + sp) * 64 + (chunk & 7) * 8) = v;
        }
    } else {
        // V path: transposed store V^T[b,h,hd,sc]
        const int b = m0 >> 11, h = ((n0 - 1024) >> 6) + wc;
        const int sp = (m0 & 2047) + wr * 64 + quad * 4;
        #pragma unroll
        for (int rt = 0; rt < 4; rt++)
            #pragma unroll
            for (int ct = 0; ct < 4; ct++) {
                short4 pk;
                pk.x = f2s(acc[rt][ct][0]); pk.y = f2s(acc[rt][ct][1]);
                pk.z = f2s(acc[rt][ct][2]); pk.w = f2s(acc[rt][ct][3]);
                int hd = ct * 16 + l15;
                *(short4*)(outV + ((size_t)(b * 16 + h) * 64 + hd) * 2048 + sp + rt * 16) = pk;
            }
    }
}

// ---------------- out-proj GEMM 128x128, K=1024 (R14 mode-2) ----------------
// grid (64,8): x = m-tile (XCD=m%8). 3-buffer counted-vmcnt pipeline.
__global__ __launch_bounds__(256, 3) void gemm_proj(
    const short* __restrict__ A,    // AO [8192][1024]
    const short* __restrict__ Bt,   // WpT [1024][1024]
    float* __restrict__ outF,
    const float* __restrict__ bias_vec) {
    __shared__ short smem[24576];
    const int tid = threadIdx.x;
    const int w = tid >> 6, lane = tid & 63, quad = lane >> 4, l15 = lane & 15;
    const int wr = w & 1, wc = w >> 1;
    const int m0 = blockIdx.x * 128, n0 = blockIdx.y * 128;

    const int srow = lane >> 2, slot = lane & 3;
    const int kslot = (slot ^ ((srow >> 1) & 3)) * 8;
    const short* Ag0 = A + (size_t)(m0 + w * 32 + srow) * 1024 + kslot;
    const short* Ag1 = Ag0 + (size_t)16 * 1024;
    const short* Bg0 = Bt + (size_t)(n0 + w * 32 + srow) * 1024 + kslot;
    const short* Bg1 = Bg0 + (size_t)16 * 1024;
    short* Al = smem + w * 1024;           // + buf*8192
    short* Bl = smem + 4096 + w * 1024;    // + buf*8192

    f32x4 acc[4][4];
    #pragma unroll
    for (int r = 0; r < 4; r++)
        #pragma unroll
        for (int c = 0; c < 4; c++) acc[r][c] = f32x4{0.f, 0.f, 0.f, 0.f};

    const int rsw = (l15 >> 1) & 3;
    const int rch = (quad ^ rsw) * 8;

    gload16(Al,              Ag0);
    gload16(Al + 512,        Ag1);
    gload16(Bl,              Bg0);
    gload16(Bl + 512,        Bg1);
    gload16(Al + 8192,       Ag0 + 32);
    gload16(Al + 8192 + 512, Ag1 + 32);
    gload16(Bl + 8192,       Bg0 + 32);
    gload16(Bl + 8192 + 512, Bg1 + 32);
    asm volatile("s_waitcnt vmcnt(4) lgkmcnt(0)" ::: "memory");
    __builtin_amdgcn_s_barrier();

    int curo = 0;
    int pfo = 16384;
    #pragma unroll 1
    for (int t = 0; t < 32; t++) {
        if (t < 30) {
            const int k0 = (t + 2) * 32;
            gload16(Al + pfo,       Ag0 + k0);
            gload16(Al + pfo + 512, Ag1 + k0);
            gload16(Bl + pfo,       Bg0 + k0);
            gload16(Bl + pfo + 512, Bg1 + k0);
        }
        bf16x8 af[4], bfr[4];
        #pragma unroll
        for (int rt = 0; rt < 4; rt++)
            af[rt] = *(const bf16x8*)(smem + curo + (wr * 64 + rt * 16 + l15) * 32 + rch);
        #pragma unroll
        for (int ct = 0; ct < 4; ct++)
            bfr[ct] = *(const bf16x8*)(smem + curo + 4096 + (wc * 64 + ct * 16 + l15) * 32 + rch);
        #pragma unroll
        for (int rt = 0; rt < 4; rt++)
            #pragma unroll
            for (int ct = 0; ct < 4; ct++)
                acc[rt][ct] = mfma16(af[rt], bfr[ct], acc[rt][ct]);
        if (t < 30) {
            asm volatile("s_waitcnt vmcnt(4) lgkmcnt(0)" ::: "memory");
        } else {
            asm volatile("s_waitcnt vmcnt(0) lgkmcnt(0)" ::: "memory");
        }
        __builtin_amdgcn_s_barrier();
        curo += 8192; if (curo == 24576) curo = 0;
        pfo  += 8192; if (pfo  == 24576) pfo  = 0;
    }

    #pragma unroll
    for (int rt = 0; rt < 4; rt++)
        #pragma unroll
        for (int i = 0; i < 4; i++) {
            size_t m = m0 + wr * 64 + rt * 16 + quad * 4 + i;
            #pragma unroll
            for (int ct = 0; ct < 4; ct++) {
                int n = n0 + wc * 64 + ct * 16 + l15;
                outF[m * 1024 + n] = acc[rt][ct][i] + bias_vec[n];
            }
        }
}

// ---------------- attention: 8-wave blocks, av-hoist + setprio ----------------
// S^T = K.Q^T with Q pre-scaled by 0.125*log2e -> p = exp2(st) (row offset
// dropped; cancels in normalization). grid (64,8), 512 threads: block covers
// 256 q-rows (wave w -> rows qt*256 + w*32). Waves 0-3 stage K, 4-7 stage V.
// LDS: K 2buf (16KB) | V 2buf (16KB) | P 8x(32x72) (36KB) = 68KB -> 2 blk/CU.
// av reads hoisted ABOVE the P fence (V-plane published at previous barrier,
// no alias with P); setprio(1) wraps the PV MFMA cluster (T5).
__global__ __launch_bounds__(512, 4) void attn_kernel(
    const short* __restrict__ Q,   // [64][2048][64]
    const short* __restrict__ K,   // [64][2048][64]
    const short* __restrict__ V,   // [64][64][2048]  (V^T)
    short* __restrict__ AO) {      // [8192][1024] bf16
    __shared__ short smem[8192 + 8192 + 8 * 32 * 72];
    const int tid = threadIdx.x;
    const int w = tid >> 6, lane = tid & 63, quad = lane >> 4, l15 = lane & 15;
    const int bh = blockIdx.x, qt = blockIdx.y;  // grid (64,8): head -> XCD = bh%8
    const short* Qb = Q + (size_t)bh * 2048 * 64;
    const short* Kb = K + (size_t)bh * 2048 * 64;
    const short* Vb = V + (size_t)bh * 64 * 2048;
    short* Pw = smem + 16384 + w * 2304;
    const int q0 = qt * 256 + w * 32;

    // staging role: waves 0-3 stage K tile rows, waves 4-7 stage V^T tile rows
    const int srow = lane >> 2, slot = lane & 3;
    const int sw = (slot ^ ((srow >> 1) & 3)) * 8;
    const int ws = w & 3;
    const bool kstager = (w < 4);
    const short* Sg = kstager ? (Kb + (size_t)(ws * 16 + srow) * 64 + sw)
                              : (Vb + (size_t)(ws * 16 + srow) * 2048 + sw);
    short* Sl0 = smem + (kstager ? 0 : 8192) + ws * 512;
    const int sstep = kstager ? 4096 : 64;  // shorts per kv-tile advance

    bf16x8 bq[2][2];  // [nt][ks]: Q as B-operand B[n=qrow][k=hd]
    #pragma unroll
    for (int nt = 0; nt < 2; nt++)
        #pragma unroll
        for (int ks = 0; ks < 2; ks++)
            bq[nt][ks] = *(const bf16x8*)(Qb + (size_t)(q0 + nt * 16 + l15) * 64 + ks * 32 + quad * 8);

    f32x4 acco[4][2];  // [ct(hd)][nt(qrow)] O^T
    #pragma unroll
    for (int ct = 0; ct < 4; ct++)
        #pragma unroll
        for (int nt = 0; nt < 2; nt++) acco[ct][nt] = f32x4{0.f, 0.f, 0.f, 0.f};
    float lsum[2] = {0.f, 0.f};
    const int rsw = (l15 >> 1) & 3;
    const int rch = (quad ^ rsw) * 8;

    gload16(Sl0,        Sg);
    gload16(Sl0 + 2048, Sg + 32);
    drain_barrier();

    #pragma unroll 1
    for (int t = 0; t < 32; t++) {
        const int cur = (t & 1) * 4096;
        if (t < 31) {
            const int nxt = 4096 - cur;
            gload16(Sl0 + nxt,        Sg + (t + 1) * sstep);
            gload16(Sl0 + nxt + 2048, Sg + (t + 1) * sstep + 32);
        }
        // ---- K and V fragments (both planes published at previous barrier;
        //      av hoisted above the P fence so its latency hides under QK) ----
        bf16x8 ak[4][2], av[4][2];
        #pragma unroll
        for (int mt = 0; mt < 4; mt++)
            #pragma unroll
            for (int ks = 0; ks < 2; ks++)
                ak[mt][ks] = *(const bf16x8*)(smem + cur + ks * 2048 + (mt * 16 + l15) * 32 + rch);
        #pragma unroll
        for (int ct = 0; ct < 4; ct++)
            #pragma unroll
            for (int ks = 0; ks < 2; ks++)
                av[ct][ks] = *(const bf16x8*)(smem + 8192 + cur + ks * 2048 + (ct * 16 + l15) * 32 + rch);

        // ---- QK^T + exp2 + P stores ----
        #pragma unroll
        for (int mt = 0; mt < 4; mt++) {
            #pragma unroll
            for (int nt = 0; nt < 2; nt++) {
                f32x4 st = f32x4{0.f, 0.f, 0.f, 0.f};
                st = mfma16(ak[mt][0], bq[nt][0], st);
                st = mfma16(ak[mt][1], bq[nt][1], st);
                float e0 = __builtin_amdgcn_exp2f(st[0]);
                float e1 = __builtin_amdgcn_exp2f(st[1]);
                float e2 = __builtin_amdgcn_exp2f(st[2]);
                float e3 = __builtin_amdgcn_exp2f(st[3]);
                lsum[nt] += (e0 + e1) + (e2 + e3);
                unsigned int p01 = __builtin_amdgcn_perm(fbits(e1), fbits(e0), 0x07060302u);
                unsigned int p23 = __builtin_amdgcn_perm(fbits(e3), fbits(e2), 0x07060302u);
                uint2 pw;
                pw.x = p01; pw.y = p23;
                *(uint2*)(Pw + (nt * 16 + l15) * 72 + mt * 16 + quad * 4) = pw;
            }
        }
        // P written via uint2*, read via bf16x8*: fence pins program order
        // (wave-local LDS ops execute in issue order -> order == correctness).
        asm volatile("" ::: "memory");

        // ---- P reads + PV ----
        bf16x8 bp[2][2];
        #pragma unroll
        for (int nt = 0; nt < 2; nt++)
            #pragma unroll
            for (int ks = 0; ks < 2; ks++)
                bp[nt][ks] = *(const bf16x8*)(Pw + (nt * 16 + l15) * 72 + ks * 32 + quad * 8);
        __builtin_amdgcn_s_setprio(1);
        #pragma unroll
        for (int ct = 0; ct < 4; ct++)
            #pragma unroll
            for (int nt = 0; nt < 2; nt++)
                #pragma unroll
                for (int ks = 0; ks < 2; ks++)
                    acco[ct][nt] = mfma16(av[ct][ks], bp[nt][ks], acco[ct][nt]);
        __builtin_amdgcn_s_setprio(0);
        drain_barrier();
    }

    #pragma unroll
    for (int nt = 0; nt < 2; nt++) {
        lsum[nt] += __shfl_xor(lsum[nt], 16, 64);
        lsum[nt] += __shfl_xor(lsum[nt], 32, 64);
    }
    const int b = bh >> 4, h = bh & 15;
    #pragma unroll
    for (int nt = 0; nt < 2; nt++) {
        float inv = 1.f / lsum[nt];
        int sq = q0 + nt * 16 + l15;
        #pragma unroll
        for (int ct = 0; ct < 4; ct++) {
            short4 pk;
            pk.x = f2s(acco[ct][nt][0] * inv); pk.y = f2s(acco[ct][nt][1] * inv);
            pk.z = f2s(acco[ct][nt][2] * inv); pk.w = f2s(acco[ct][nt][3] * inv);
            *(short4*)(AO + ((size_t)b * 2048 + sq) * 1024 + h * 64 + ct * 16 + quad * 4) = pk;
        }
    }
}

extern "C" void kernel_launch(void* const* d_in, const int* in_sizes, int n_in,
                              void* d_out, int out_size, void* d_ws, size_t ws_size,
                              hipStream_t stream) {
    (void)in_sizes; (void)n_in; (void)out_size; (void)ws_size;
    const float* x      = (const float*)d_in[0];
    const float* ctx    = (const float*)d_in[1];
    const float* q_w    = (const float*)d_in[2];
    const float* kv_w   = (const float*)d_in[3];
    const float* qn_s   = (const float*)d_in[4];
    const float* qn_b   = (const float*)d_in[5];
    const float* kn_s   = (const float*)d_in[6];
    const float* kn_b   = (const float*)d_in[7];
    const float* proj_w = (const float*)d_in[8];
    const float* proj_b = (const float*)d_in[9];
    float* out = (float*)d_out;

    char* ws = (char*)d_ws;
    const size_t MB = 1024 * 1024;
    short* xb   = (short*)(ws + 0 * MB);
    short* cb   = (short*)(ws + 16 * MB);
    short* Qb   = (short*)(ws + 32 * MB);   // [64][2048][64] post LN+RoPE+scale
    short* Kb   = (short*)(ws + 48 * MB);   // [64][2048][64] post LN
    short* Vt   = (short*)(ws + 64 * MB);   // [64][64][2048]
    short* AO   = (short*)(ws + 80 * MB);   // [8192][1024]
    short* WqT  = (short*)(ws + 96 * MB);   // 2MB
    short* WkvT = (short*)(ws + 98 * MB);   // 4MB  [2048][1024]
    short* WpT  = (short*)(ws + 102 * MB);  // 2MB

    conv_to_bf16<<<16384, 256, 0, stream>>>(x, ctx, xb, cb);
    transpose_weights<<<dim3(32, 32, 4), 256, 0, stream>>>(q_w, kv_w, proj_w, WqT, WkvT, WpT);
    gemm_qkv<<<dim3(64, 24), 256, 0, stream>>>(xb, WqT, cb, WkvT, qn_s, qn_b, kn_s, kn_b,
                                               Qb, Kb, Vt);
    attn_kernel<<<dim3(64, 8), 512, 0, stream>>>(Qb, Kb, Vt, AO);
    gemm_proj<<<dim3(64, 8), 256, 0, stream>>>(AO, WpT, out, proj_b);
}

// Round 14
// 295.829 us; speedup vs baseline: 1.0683x; 1.0683x over previous
//
#include <hip/hip_runtime.h>
#include <hip/hip_bf16.h>

// CrossAttention R20 = R14 exact + (a) setprio-only in attn PV, (b) merged prep.
//  - R19 post-mortem: av-hoist caused SCRATCH SPILLS (attn WRITE_SIZE 16.4->
//    27.6MB = +11MB scratch; dur 85.8->98.2). Hoisting loads is only free if
//    registers are. Reverted attn to R14 phase order (av read after fence,
//    short live range).
//  - Change 1 (attn): s_setprio(1) around PV MFMA cluster ONLY (T5; no reg
//    pressure; R19's spill masked its effect).
//  - Change 2 (prep): conv_to_bf16 + transpose_weights merged into one
//    dispatch (blocks 0-16383 conv, 16384-20479 transpose) -- one less
//    launch, transpose fills conv's tail. Independently attributable.
//  - qkv: R14 3-buf counted. proj: R14 mode-2. Both untouched.

typedef short bf16x8 __attribute__((ext_vector_type(8)));
typedef float f32x4 __attribute__((ext_vector_type(4)));

__device__ __forceinline__ short f2s(float f) {
    __hip_bfloat16 h = __float2bfloat16(f);
    return __builtin_bit_cast(short, h);
}

__device__ __forceinline__ f32x4 mfma16(bf16x8 a, bf16x8 b, f32x4 c) {
    return __builtin_amdgcn_mfma_f32_16x16x32_bf16(a, b, c, 0, 0, 0);
}

__device__ __forceinline__ void gload16(short* lds, const short* g) {
    __builtin_amdgcn_global_load_lds((const __attribute__((address_space(1))) void*)g,
                                     (__attribute__((address_space(3))) void*)lds,
                                     16, 0, 0);
}

// Barrier with guaranteed counter drain (correctness of single-barrier dbuf).
__device__ __forceinline__ void drain_barrier() {
    asm volatile("s_waitcnt vmcnt(0) lgkmcnt(0)" ::: "memory");
    __syncthreads();
}

__device__ __forceinline__ unsigned int fbits(float f) {
    return __builtin_bit_cast(unsigned int, f);
}

// ---------------- prep (merged): fp32->bf16 activations + W->W^T bf16 ----------------
// blocks [0, 16384): conv  -- thread i converts one float4 of x (i<NV) or ctx.
// blocks [16384, 20480): transpose -- flat r = bid-16384: z=r>>10 selects matrix,
// x=r&31, y=(r>>5)&31 are the 32x32 tile coords (same mapping as dim3(32,32,4)).
__global__ __launch_bounds__(256) void prep_kernel(
    const float* __restrict__ x, const float* __restrict__ ctx,
    short* __restrict__ xb, short* __restrict__ cb,
    const float* __restrict__ q_w, const float* __restrict__ kv_w,
    const float* __restrict__ proj_w,
    short* __restrict__ WqT, short* __restrict__ WkvT, short* __restrict__ WpT) {
    __shared__ float t[32][33];
    const int bid = blockIdx.x;
    if (bid < 16384) {
        const size_t NV = 2097152;
        size_t i = (size_t)bid * 256 + threadIdx.x;
        const float4* src = (i < NV) ? (const float4*)x : (const float4*)ctx;
        short* dst = (i < NV) ? xb : cb;
        size_t idx = (i < NV) ? i : i - NV;
        float4 v = src[idx];
        short4 o;
        o.x = f2s(v.x); o.y = f2s(v.y); o.z = f2s(v.z); o.w = f2s(v.w);
        ((short4*)dst)[idx] = o;
        return;
    }
    const int r = bid - 16384;
    const int bz = r >> 10, bx = r & 31, by = (r >> 5) & 31;
    const float* src; short* dst; int ld, coff;
    switch (bz) {
        case 0:  src = q_w;    dst = WqT;                 ld = 1024; coff = 0;    break;
        case 1:  src = kv_w;   dst = WkvT;                ld = 2048; coff = 0;    break;
        case 2:  src = kv_w;   dst = WkvT + 1024 * 1024;  ld = 2048; coff = 1024; break;
        default: src = proj_w; dst = WpT;                 ld = 1024; coff = 0;    break;
    }
    int n0 = bx * 32, k0 = by * 32;
    int tx = threadIdx.x & 31, ty = threadIdx.x >> 5;
    #pragma unroll
    for (int j = 0; j < 32; j += 8)
        t[ty + j][tx] = src[(size_t)(k0 + ty + j) * ld + coff + n0 + tx];
    __syncthreads();
    #pragma unroll
    for (int j = 0; j < 32; j += 8)
        dst[(size_t)(n0 + ty + j) * 1024 + k0 + tx] = f2s(t[tx][ty + j]);
}

// ---------------- fused QKV GEMM 128x128, K=1024, 3-buffer counted pipeline ----------------
// grid (64,24): x = m-tile (XCD=m%8). y<8: Q path (LN(qn)+RoPE+scale -> outQ);
// y>=8: KV path (n0=(y-8)*128; n0<1024: LN(kn) -> outK; else V^T -> outV).
__global__ __launch_bounds__(256, 3) void gemm_qkv(
    const short* __restrict__ A,      // xb
    const short* __restrict__ Bt,     // WqT
    const short* __restrict__ A2,     // cb
    const short* __restrict__ Bt2,    // WkvT
    const float* __restrict__ qn_scale, const float* __restrict__ qn_bias,
    const float* __restrict__ kn_scale, const float* __restrict__ kn_bias,
    short* __restrict__ outQ, short* __restrict__ outK, short* __restrict__ outV) {
    __shared__ short smem[24576];
    const int tid = threadIdx.x;
    const int w = tid >> 6, lane = tid & 63, quad = lane >> 4, l15 = lane & 15;
    const int wr = w & 1, wc = w >> 1;
    const int m0 = blockIdx.x * 128;  // x=m (XCD=m%8)

    const int y = blockIdx.y;
    const bool qpath = (y < 8);
    const int n0 = qpath ? y * 128 : (y - 8) * 128;
    const short* Ab = qpath ? A : A2;
    const short* Bb = qpath ? Bt : Bt2;
    const float* lns = qpath ? qn_scale : kn_scale;
    const float* lnb = qpath ? qn_bias : kn_bias;
    const bool vpath = (!qpath) && (n0 >= 1024);

    const int srow = lane >> 2, slot = lane & 3;
    const int kslot = (slot ^ ((srow >> 1) & 3)) * 8;  // XOR swizzle: 2-way banks on read
    const short* Ag0 = Ab + (size_t)(m0 + w * 32 + srow) * 1024 + kslot;
    const short* Ag1 = Ag0 + (size_t)16 * 1024;
    const short* Bg0 = Bb + (size_t)(n0 + w * 32 + srow) * 1024 + kslot;
    const short* Bg1 = Bg0 + (size_t)16 * 1024;
    short* Al = smem + w * 1024;           // + buf*8192
    short* Bl = smem + 4096 + w * 1024;    // + buf*8192

    f32x4 acc[4][4];
    #pragma unroll
    for (int r = 0; r < 4; r++)
        #pragma unroll
        for (int c = 0; c < 4; c++) acc[r][c] = f32x4{0.f, 0.f, 0.f, 0.f};

    const int rsw = (l15 >> 1) & 3;
    const int rch = (quad ^ rsw) * 8;

    // prologue: tile 0 -> buf0, tile 1 -> buf1; wait oldest 4 (tile 0) only.
    gload16(Al,              Ag0);
    gload16(Al + 512,        Ag1);
    gload16(Bl,              Bg0);
    gload16(Bl + 512,        Bg1);
    gload16(Al + 8192,       Ag0 + 32);
    gload16(Al + 8192 + 512, Ag1 + 32);
    gload16(Bl + 8192,       Bg0 + 32);
    gload16(Bl + 8192 + 512, Bg1 + 32);
    asm volatile("s_waitcnt vmcnt(4) lgkmcnt(0)" ::: "memory");
    __builtin_amdgcn_s_barrier();

    int curo = 0;       // current compute buffer offset (shorts)
    int pfo = 16384;    // prefetch target buffer offset (tile t+2)
    #pragma unroll 1
    for (int t = 0; t < 32; t++) {
        if (t < 30) {
            const int k0 = (t + 2) * 32;
            gload16(Al + pfo,       Ag0 + k0);
            gload16(Al + pfo + 512, Ag1 + k0);
            gload16(Bl + pfo,       Bg0 + k0);
            gload16(Bl + pfo + 512, Bg1 + k0);
        }
        bf16x8 af[4], bfr[4];
        #pragma unroll
        for (int rt = 0; rt < 4; rt++)
            af[rt] = *(const bf16x8*)(smem + curo + (wr * 64 + rt * 16 + l15) * 32 + rch);
        #pragma unroll
        for (int ct = 0; ct < 4; ct++)
            bfr[ct] = *(const bf16x8*)(smem + curo + 4096 + (wc * 64 + ct * 16 + l15) * 32 + rch);
        #pragma unroll
        for (int rt = 0; rt < 4; rt++)
            #pragma unroll
            for (int ct = 0; ct < 4; ct++)
                acc[rt][ct] = mfma16(af[rt], bfr[ct], acc[rt][ct]);
        if (t < 30) {
            asm volatile("s_waitcnt vmcnt(4) lgkmcnt(0)" ::: "memory");
        } else {
            asm volatile("s_waitcnt vmcnt(0) lgkmcnt(0)" ::: "memory");
        }
        __builtin_amdgcn_s_barrier();
        curo += 8192; if (curo == 24576) curo = 0;
        pfo  += 8192; if (pfo  == 24576) pfo  = 0;
    }

    // epilogue: lane holds C[row = wr*64+rt*16+quad*4+i][col = wc*64+ct*16+l15]
    if (!vpath) {
        #pragma unroll
        for (int rt = 0; rt < 4; rt++) {
            #pragma unroll
            for (int i = 0; i < 4; i++) {
                float s = acc[rt][0][i] + acc[rt][1][i] + acc[rt][2][i] + acc[rt][3][i];
                float q = acc[rt][0][i] * acc[rt][0][i] + acc[rt][1][i] * acc[rt][1][i] +
                          acc[rt][2][i] * acc[rt][2][i] + acc[rt][3][i] * acc[rt][3][i];
                #pragma unroll
                for (int off = 1; off < 16; off <<= 1) {
                    s += __shfl_xor(s, off, 64);
                    q += __shfl_xor(q, off, 64);
                }
                float mu = s * (1.f / 64.f);
                float var = q * (1.f / 64.f) - mu * mu;
                float rs = rsqrtf(var + 1e-5f);
                float vals[4];
                #pragma unroll
                for (int ct = 0; ct < 4; ct++) {
                    int hd = ct * 16 + l15;
                    vals[ct] = (acc[rt][ct][i] - mu) * rs * lns[hd] + lnb[hd];
                }
                if (qpath) {  // RoPE pairs (hd, hd+32) = (ct, ct+2), then *0.125*log2e
                    int sp = (m0 + wr * 64 + rt * 16 + quad * 4 + i) & 2047;
                    #pragma unroll
                    for (int ct = 0; ct < 2; ct++) {
                        int hd1 = ct * 16 + l15;
                        float ang = (float)sp * exp2f((float)hd1 * (-13.287712379549449f / 32.f));
                        float sn, cs;
                        sincosf(ang, &sn, &cs);
                        float v1 = vals[ct], v2 = vals[ct + 2];
                        vals[ct]     = v1 * cs - v2 * sn;
                        vals[ct + 2] = v1 * sn + v2 * cs;
                    }
                    #pragma unroll
                    for (int ct = 0; ct < 4; ct++) vals[ct] *= 0.1803368801f;
                }
                #pragma unroll
                for (int ct = 0; ct < 4; ct++) acc[rt][ct][i] = vals[ct];
            }
        }
        drain_barrier();
        short* Csm = smem;  // overlay: [128][132] bf16, +4 pad
        #pragma unroll
        for (int rt = 0; rt < 4; rt++)
            #pragma unroll
            for (int ct = 0; ct < 4; ct++)
                #pragma unroll
                for (int i = 0; i < 4; i++)
                    Csm[(wr * 64 + rt * 16 + quad * 4 + i) * 132 + wc * 64 + ct * 16 + l15] =
                        f2s(acc[rt][ct][i]);
        drain_barrier();
        short* dst = qpath ? outQ : outK;
        #pragma unroll
        for (int it = 0; it < 8; it++) {
            int row = it * 16 + (tid >> 4);
            int chunk = tid & 15;
            bf16x8 v = *(const bf16x8*)(Csm + row * 132 + chunk * 8);
            int hh = ((n0 & 1023) >> 6) + (chunk >> 3);
            int m = m0 + row, b = m >> 11, sp = m & 2047;
            *(bf16x8*)(dst + ((size_t)(b * 16 + hh) * 2048 + sp) * 64 + (chunk & 7) * 8) = v;
        }
    } else {
        // V path: transposed store V^T[b,h,hd,sc]
        const int b = m0 >> 11, h = ((n0 - 1024) >> 6) + wc;
        const int sp = (m0 & 2047) + wr * 64 + quad * 4;
        #pragma unroll
        for (int rt = 0; rt < 4; rt++)
            #pragma unroll
            for (int ct = 0; ct < 4; ct++) {
                short4 pk;
                pk.x = f2s(acc[rt][ct][0]); pk.y = f2s(acc[rt][ct][1]);
                pk.z = f2s(acc[rt][ct][2]); pk.w = f2s(acc[rt][ct][3]);
                int hd = ct * 16 + l15;
                *(short4*)(outV + ((size_t)(b * 16 + h) * 64 + hd) * 2048 + sp + rt * 16) = pk;
            }
    }
}

// ---------------- out-proj GEMM 128x128, K=1024 (R14 mode-2) ----------------
// grid (64,8): x = m-tile (XCD=m%8). 3-buffer counted-vmcnt pipeline.
__global__ __launch_bounds__(256, 3) void gemm_proj(
    const short* __restrict__ A,    // AO [8192][1024]
    const short* __restrict__ Bt,   // WpT [1024][1024]
    float* __restrict__ outF,
    const float* __restrict__ bias_vec) {
    __shared__ short smem[24576];
    const int tid = threadIdx.x;
    const int w = tid >> 6, lane = tid & 63, quad = lane >> 4, l15 = lane & 15;
    const int wr = w & 1, wc = w >> 1;
    const int m0 = blockIdx.x * 128, n0 = blockIdx.y * 128;

    const int srow = lane >> 2, slot = lane & 3;
    const int kslot = (slot ^ ((srow >> 1) & 3)) * 8;
    const short* Ag0 = A + (size_t)(m0 + w * 32 + srow) * 1024 + kslot;
    const short* Ag1 = Ag0 + (size_t)16 * 1024;
    const short* Bg0 = Bt + (size_t)(n0 + w * 32 + srow) * 1024 + kslot;
    const short* Bg1 = Bg0 + (size_t)16 * 1024;
    short* Al = smem + w * 1024;           // + buf*8192
    short* Bl = smem + 4096 + w * 1024;    // + buf*8192

    f32x4 acc[4][4];
    #pragma unroll
    for (int r = 0; r < 4; r++)
        #pragma unroll
        for (int c = 0; c < 4; c++) acc[r][c] = f32x4{0.f, 0.f, 0.f, 0.f};

    const int rsw = (l15 >> 1) & 3;
    const int rch = (quad ^ rsw) * 8;

    gload16(Al,              Ag0);
    gload16(Al + 512,        Ag1);
    gload16(Bl,              Bg0);
    gload16(Bl + 512,        Bg1);
    gload16(Al + 8192,       Ag0 + 32);
    gload16(Al + 8192 + 512, Ag1 + 32);
    gload16(Bl + 8192,       Bg0 + 32);
    gload16(Bl + 8192 + 512, Bg1 + 32);
    asm volatile("s_waitcnt vmcnt(4) lgkmcnt(0)" ::: "memory");
    __builtin_amdgcn_s_barrier();

    int curo = 0;
    int pfo = 16384;
    #pragma unroll 1
    for (int t = 0; t < 32; t++) {
        if (t < 30) {
            const int k0 = (t + 2) * 32;
            gload16(Al + pfo,       Ag0 + k0);
            gload16(Al + pfo + 512, Ag1 + k0);
            gload16(Bl + pfo,       Bg0 + k0);
            gload16(Bl + pfo + 512, Bg1 + k0);
        }
        bf16x8 af[4], bfr[4];
        #pragma unroll
        for (int rt = 0; rt < 4; rt++)
            af[rt] = *(const bf16x8*)(smem + curo + (wr * 64 + rt * 16 + l15) * 32 + rch);
        #pragma unroll
        for (int ct = 0; ct < 4; ct++)
            bfr[ct] = *(const bf16x8*)(smem + curo + 4096 + (wc * 64 + ct * 16 + l15) * 32 + rch);
        #pragma unroll
        for (int rt = 0; rt < 4; rt++)
            #pragma unroll
            for (int ct = 0; ct < 4; ct++)
                acc[rt][ct] = mfma16(af[rt], bfr[ct], acc[rt][ct]);
        if (t < 30) {
            asm volatile("s_waitcnt vmcnt(4) lgkmcnt(0)" ::: "memory");
        } else {
            asm volatile("s_waitcnt vmcnt(0) lgkmcnt(0)" ::: "memory");
        }
        __builtin_amdgcn_s_barrier();
        curo += 8192; if (curo == 24576) curo = 0;
        pfo  += 8192; if (pfo  == 24576) pfo  = 0;
    }

    #pragma unroll
    for (int rt = 0; rt < 4; rt++)
        #pragma unroll
        for (int i = 0; i < 4; i++) {
            size_t m = m0 + wr * 64 + rt * 16 + quad * 4 + i;
            #pragma unroll
            for (int ct = 0; ct < 4; ct++) {
                int n = n0 + wc * 64 + ct * 16 + l15;
                outF[m * 1024 + n] = acc[rt][ct][i] + bias_vec[n];
            }
        }
}

// ---------------- attention: 8-wave blocks (R14 order) + PV setprio ----------------
// S^T = K.Q^T with Q pre-scaled by 0.125*log2e -> p = exp2(st) (row offset
// dropped; cancels in normalization). grid (64,8), 512 threads: block covers
// 256 q-rows (wave w -> rows qt*256 + w*32). Waves 0-3 stage K, 4-7 stage V.
// LDS: K 2buf (16KB) | V 2buf (16KB) | P 8x(32x72) (36KB) = 68KB -> 2 blk/CU.
// av reads stay AFTER the fence (R14 order: short live range, no spills).
__global__ __launch_bounds__(512, 4) void attn_kernel(
    const short* __restrict__ Q,   // [64][2048][64]
    const short* __restrict__ K,   // [64][2048][64]
    const short* __restrict__ V,   // [64][64][2048]  (V^T)
    short* __restrict__ AO) {      // [8192][1024] bf16
    __shared__ short smem[8192 + 8192 + 8 * 32 * 72];
    const int tid = threadIdx.x;
    const int w = tid >> 6, lane = tid & 63, quad = lane >> 4, l15 = lane & 15;
    const int bh = blockIdx.x, qt = blockIdx.y;  // grid (64,8): head -> XCD = bh%8
    const short* Qb = Q + (size_t)bh * 2048 * 64;
    const short* Kb = K + (size_t)bh * 2048 * 64;
    const short* Vb = V + (size_t)bh * 64 * 2048;
    short* Pw = smem + 16384 + w * 2304;
    const int q0 = qt * 256 + w * 32;

    // staging role: waves 0-3 stage K tile rows, waves 4-7 stage V^T tile rows
    const int srow = lane >> 2, slot = lane & 3;
    const int sw = (slot ^ ((srow >> 1) & 3)) * 8;
    const int ws = w & 3;
    const bool kstager = (w < 4);
    const short* Sg = kstager ? (Kb + (size_t)(ws * 16 + srow) * 64 + sw)
                              : (Vb + (size_t)(ws * 16 + srow) * 2048 + sw);
    short* Sl0 = smem + (kstager ? 0 : 8192) + ws * 512;
    const int sstep = kstager ? 4096 : 64;  // shorts per kv-tile advance

    bf16x8 bq[2][2];  // [nt][ks]: Q as B-operand B[n=qrow][k=hd]
    #pragma unroll
    for (int nt = 0; nt < 2; nt++)
        #pragma unroll
        for (int ks = 0; ks < 2; ks++)
            bq[nt][ks] = *(const bf16x8*)(Qb + (size_t)(q0 + nt * 16 + l15) * 64 + ks * 32 + quad * 8);

    f32x4 acco[4][2];  // [ct(hd)][nt(qrow)] O^T
    #pragma unroll
    for (int ct = 0; ct < 4; ct++)
        #pragma unroll
        for (int nt = 0; nt < 2; nt++) acco[ct][nt] = f32x4{0.f, 0.f, 0.f, 0.f};
    float lsum[2] = {0.f, 0.f};
    const int rsw = (l15 >> 1) & 3;
    const int rch = (quad ^ rsw) * 8;

    gload16(Sl0,        Sg);
    gload16(Sl0 + 2048, Sg + 32);
    drain_barrier();

    #pragma unroll 1
    for (int t = 0; t < 32; t++) {
        const int cur = (t & 1) * 4096;
        if (t < 31) {
            const int nxt = 4096 - cur;
            gload16(Sl0 + nxt,        Sg + (t + 1) * sstep);
            gload16(Sl0 + nxt + 2048, Sg + (t + 1) * sstep + 32);
        }
        // ---- K fragments, QK^T + exp2 + P stores ----
        bf16x8 ak[4][2];
        #pragma unroll
        for (int mt = 0; mt < 4; mt++)
            #pragma unroll
            for (int ks = 0; ks < 2; ks++)
                ak[mt][ks] = *(const bf16x8*)(smem + cur + ks * 2048 + (mt * 16 + l15) * 32 + rch);

        #pragma unroll
        for (int mt = 0; mt < 4; mt++) {
            #pragma unroll
            for (int nt = 0; nt < 2; nt++) {
                f32x4 st = f32x4{0.f, 0.f, 0.f, 0.f};
                st = mfma16(ak[mt][0], bq[nt][0], st);
                st = mfma16(ak[mt][1], bq[nt][1], st);
                float e0 = __builtin_amdgcn_exp2f(st[0]);
                float e1 = __builtin_amdgcn_exp2f(st[1]);
                float e2 = __builtin_amdgcn_exp2f(st[2]);
                float e3 = __builtin_amdgcn_exp2f(st[3]);
                lsum[nt] += (e0 + e1) + (e2 + e3);
                unsigned int p01 = __builtin_amdgcn_perm(fbits(e1), fbits(e0), 0x07060302u);
                unsigned int p23 = __builtin_amdgcn_perm(fbits(e3), fbits(e2), 0x07060302u);
                uint2 pw;
                pw.x = p01; pw.y = p23;
                *(uint2*)(Pw + (nt * 16 + l15) * 72 + mt * 16 + quad * 4) = pw;
            }
        }
        // P written via uint2*, read via bf16x8*: fence pins program order
        // (wave-local LDS ops execute in issue order -> order == correctness).
        asm volatile("" ::: "memory");

        // ---- V fragments, P reads + PV ----
        bf16x8 av[4][2];
        #pragma unroll
        for (int ct = 0; ct < 4; ct++)
            #pragma unroll
            for (int ks = 0; ks < 2; ks++)
                av[ct][ks] = *(const bf16x8*)(smem + 8192 + cur + ks * 2048 + (ct * 16 + l15) * 32 + rch);

        bf16x8 bp[2][2];
        #pragma unroll
        for (int nt = 0; nt < 2; nt++)
            #pragma unroll
            for (int ks = 0; ks < 2; ks++)
                bp[nt][ks] = *(const bf16x8*)(Pw + (nt * 16 + l15) * 72 + ks * 32 + quad * 8);
        __builtin_amdgcn_s_setprio(1);
        #pragma unroll
        for (int ct = 0; ct < 4; ct++)
            #pragma unroll
            for (int nt = 0; nt < 2; nt++)
                #pragma unroll
                for (int ks = 0; ks < 2; ks++)
                    acco[ct][nt] = mfma16(av[ct][ks], bp[nt][ks], acco[ct][nt]);
        __builtin_amdgcn_s_setprio(0);
        drain_barrier();
    }

    #pragma unroll
    for (int nt = 0; nt < 2; nt++) {
        lsum[nt] += __shfl_xor(lsum[nt], 16, 64);
        lsum[nt] += __shfl_xor(lsum[nt], 32, 64);
    }
    const int b = bh >> 4, h = bh & 15;
    #pragma unroll
    for (int nt = 0; nt < 2; nt++) {
        float inv = 1.f / lsum[nt];
        int sq = q0 + nt * 16 + l15;
        #pragma unroll
        for (int ct = 0; ct < 4; ct++) {
            short4 pk;
            pk.x = f2s(acco[ct][nt][0] * inv); pk.y = f2s(acco[ct][nt][1] * inv);
            pk.z = f2s(acco[ct][nt][2] * inv); pk.w = f2s(acco[ct][nt][3] * inv);
            *(short4*)(AO + ((size_t)b * 2048 + sq) * 1024 + h * 64 + ct * 16 + quad * 4) = pk;
        }
    }
}

extern "C" void kernel_launch(void* const* d_in, const int* in_sizes, int n_in,
                              void* d_out, int out_size, void* d_ws, size_t ws_size,
                              hipStream_t stream) {
    (void)in_sizes; (void)n_in; (void)out_size; (void)ws_size;
    const float* x      = (const float*)d_in[0];
    const float* ctx    = (const float*)d_in[1];
    const float* q_w    = (const float*)d_in[2];
    const float* kv_w   = (const float*)d_in[3];
    const float* qn_s   = (const float*)d_in[4];
    const float* qn_b   = (const float*)d_in[5];
    const float* kn_s   = (const float*)d_in[6];
    const float* kn_b   = (const float*)d_in[7];
    const float* proj_w = (const float*)d_in[8];
    const float* proj_b = (const float*)d_in[9];
    float* out = (float*)d_out;

    char* ws = (char*)d_ws;
    const size_t MB = 1024 * 1024;
    short* xb   = (short*)(ws + 0 * MB);
    short* cb   = (short*)(ws + 16 * MB);
    short* Qb   = (short*)(ws + 32 * MB);   // [64][2048][64] post LN+RoPE+scale
    short* Kb   = (short*)(ws + 48 * MB);   // [64][2048][64] post LN
    short* Vt   = (short*)(ws + 64 * MB);   // [64][64][2048]
    short* AO   = (short*)(ws + 80 * MB);   // [8192][1024]
    short* WqT  = (short*)(ws + 96 * MB);   // 2MB
    short* WkvT = (short*)(ws + 98 * MB);   // 4MB  [2048][1024]
    short* WpT  = (short*)(ws + 102 * MB);  // 2MB

    prep_kernel<<<20480, 256, 0, stream>>>(x, ctx, xb, cb, q_w, kv_w, proj_w, WqT, WkvT, WpT);
    gemm_qkv<<<dim3(64, 24), 256, 0, stream>>>(xb, WqT, cb, WkvT, qn_s, qn_b, kn_s, kn_b,
                                               Qb, Kb, Vt);
    attn_kernel<<<dim3(64, 8), 512, 0, stream>>>(Qb, Kb, Vt, AO);
    gemm_proj<<<dim3(64, 8), 256, 0, stream>>>(AO, WpT, out, proj_b);
}

// Round 15
// 295.380 us; speedup vs baseline: 1.0700x; 1.0015x over previous
//
#include <hip/hip_runtime.h>
#include <hip/hip_bf16.h>

// CrossAttention R21 = R20 minus attn setprio (single-variable revert).
//  - R20 post-mortem: merged prep won (~4us). But attn WITH setprio = 88.1us
//    vs 84.7-85.8 in R11/R17 WITHOUT (same structure, no spills) -- setprio
//    is ~3us NEGATIVE here, consistent with m190 (T5 null without true
//    phase-split; our lockstep-barrier loop doesn't qualify).
//  - attn: exact R14/R17 loop (no setprio). prep: merged (R20). qkv: 3-buf
//    counted (proven). proj: R14 mode-2. All else byte-identical to R20.
//  - attn accounting at ~85us: MFMA 33% + VALU 40% + ~10% P-tile bank
//    conflicts (no safe 16B-aligned stride fixes gcd(S,32)>=4) + ~17%
//    barrier skew; prefetch latency fully covered by ~6.6K-cyc iters.

typedef short bf16x8 __attribute__((ext_vector_type(8)));
typedef float f32x4 __attribute__((ext_vector_type(4)));

__device__ __forceinline__ short f2s(float f) {
    __hip_bfloat16 h = __float2bfloat16(f);
    return __builtin_bit_cast(short, h);
}

__device__ __forceinline__ f32x4 mfma16(bf16x8 a, bf16x8 b, f32x4 c) {
    return __builtin_amdgcn_mfma_f32_16x16x32_bf16(a, b, c, 0, 0, 0);
}

__device__ __forceinline__ void gload16(short* lds, const short* g) {
    __builtin_amdgcn_global_load_lds((const __attribute__((address_space(1))) void*)g,
                                     (__attribute__((address_space(3))) void*)lds,
                                     16, 0, 0);
}

// Barrier with guaranteed counter drain (correctness of single-barrier dbuf).
__device__ __forceinline__ void drain_barrier() {
    asm volatile("s_waitcnt vmcnt(0) lgkmcnt(0)" ::: "memory");
    __syncthreads();
}

__device__ __forceinline__ unsigned int fbits(float f) {
    return __builtin_bit_cast(unsigned int, f);
}

// ---------------- prep (merged): fp32->bf16 activations + W->W^T bf16 ----------------
// blocks [0, 16384): conv  -- thread i converts one float4 of x (i<NV) or ctx.
// blocks [16384, 20480): transpose -- flat r = bid-16384: z=r>>10 selects matrix,
// x=r&31, y=(r>>5)&31 are the 32x32 tile coords (same mapping as dim3(32,32,4)).
__global__ __launch_bounds__(256) void prep_kernel(
    const float* __restrict__ x, const float* __restrict__ ctx,
    short* __restrict__ xb, short* __restrict__ cb,
    const float* __restrict__ q_w, const float* __restrict__ kv_w,
    const float* __restrict__ proj_w,
    short* __restrict__ WqT, short* __restrict__ WkvT, short* __restrict__ WpT) {
    __shared__ float t[32][33];
    const int bid = blockIdx.x;
    if (bid < 16384) {
        const size_t NV = 2097152;
        size_t i = (size_t)bid * 256 + threadIdx.x;
        const float4* src = (i < NV) ? (const float4*)x : (const float4*)ctx;
        short* dst = (i < NV) ? xb : cb;
        size_t idx = (i < NV) ? i : i - NV;
        float4 v = src[idx];
        short4 o;
        o.x = f2s(v.x); o.y = f2s(v.y); o.z = f2s(v.z); o.w = f2s(v.w);
        ((short4*)dst)[idx] = o;
        return;
    }
    const int r = bid - 16384;
    const int bz = r >> 10, bx = r & 31, by = (r >> 5) & 31;
    const float* src; short* dst; int ld, coff;
    switch (bz) {
        case 0:  src = q_w;    dst = WqT;                 ld = 1024; coff = 0;    break;
        case 1:  src = kv_w;   dst = WkvT;                ld = 2048; coff = 0;    break;
        case 2:  src = kv_w;   dst = WkvT + 1024 * 1024;  ld = 2048; coff = 1024; break;
        default: src = proj_w; dst = WpT;                 ld = 1024; coff = 0;    break;
    }
    int n0 = bx * 32, k0 = by * 32;
    int tx = threadIdx.x & 31, ty = threadIdx.x >> 5;
    #pragma unroll
    for (int j = 0; j < 32; j += 8)
        t[ty + j][tx] = src[(size_t)(k0 + ty + j) * ld + coff + n0 + tx];
    __syncthreads();
    #pragma unroll
    for (int j = 0; j < 32; j += 8)
        dst[(size_t)(n0 + ty + j) * 1024 + k0 + tx] = f2s(t[tx][ty + j]);
}

// ---------------- fused QKV GEMM 128x128, K=1024, 3-buffer counted pipeline ----------------
// grid (64,24): x = m-tile (XCD=m%8). y<8: Q path (LN(qn)+RoPE+scale -> outQ);
// y>=8: KV path (n0=(y-8)*128; n0<1024: LN(kn) -> outK; else V^T -> outV).
__global__ __launch_bounds__(256, 3) void gemm_qkv(
    const short* __restrict__ A,      // xb
    const short* __restrict__ Bt,     // WqT
    const short* __restrict__ A2,     // cb
    const short* __restrict__ Bt2,    // WkvT
    const float* __restrict__ qn_scale, const float* __restrict__ qn_bias,
    const float* __restrict__ kn_scale, const float* __restrict__ kn_bias,
    short* __restrict__ outQ, short* __restrict__ outK, short* __restrict__ outV) {
    __shared__ short smem[24576];
    const int tid = threadIdx.x;
    const int w = tid >> 6, lane = tid & 63, quad = lane >> 4, l15 = lane & 15;
    const int wr = w & 1, wc = w >> 1;
    const int m0 = blockIdx.x * 128;  // x=m (XCD=m%8)

    const int y = blockIdx.y;
    const bool qpath = (y < 8);
    const int n0 = qpath ? y * 128 : (y - 8) * 128;
    const short* Ab = qpath ? A : A2;
    const short* Bb = qpath ? Bt : Bt2;
    const float* lns = qpath ? qn_scale : kn_scale;
    const float* lnb = qpath ? qn_bias : kn_bias;
    const bool vpath = (!qpath) && (n0 >= 1024);

    const int srow = lane >> 2, slot = lane & 3;
    const int kslot = (slot ^ ((srow >> 1) & 3)) * 8;  // XOR swizzle: 2-way banks on read
    const short* Ag0 = Ab + (size_t)(m0 + w * 32 + srow) * 1024 + kslot;
    const short* Ag1 = Ag0 + (size_t)16 * 1024;
    const short* Bg0 = Bb + (size_t)(n0 + w * 32 + srow) * 1024 + kslot;
    const short* Bg1 = Bg0 + (size_t)16 * 1024;
    short* Al = smem + w * 1024;           // + buf*8192
    short* Bl = smem + 4096 + w * 1024;    // + buf*8192

    f32x4 acc[4][4];
    #pragma unroll
    for (int r = 0; r < 4; r++)
        #pragma unroll
        for (int c = 0; c < 4; c++) acc[r][c] = f32x4{0.f, 0.f, 0.f, 0.f};

    const int rsw = (l15 >> 1) & 3;
    const int rch = (quad ^ rsw) * 8;

    // prologue: tile 0 -> buf0, tile 1 -> buf1; wait oldest 4 (tile 0) only.
    gload16(Al,              Ag0);
    gload16(Al + 512,        Ag1);
    gload16(Bl,              Bg0);
    gload16(Bl + 512,        Bg1);
    gload16(Al + 8192,       Ag0 + 32);
    gload16(Al + 8192 + 512, Ag1 + 32);
    gload16(Bl + 8192,       Bg0 + 32);
    gload16(Bl + 8192 + 512, Bg1 + 32);
    asm volatile("s_waitcnt vmcnt(4) lgkmcnt(0)" ::: "memory");
    __builtin_amdgcn_s_barrier();

    int curo = 0;       // current compute buffer offset (shorts)
    int pfo = 16384;    // prefetch target buffer offset (tile t+2)
    #pragma unroll 1
    for (int t = 0; t < 32; t++) {
        if (t < 30) {
            const int k0 = (t + 2) * 32;
            gload16(Al + pfo,       Ag0 + k0);
            gload16(Al + pfo + 512, Ag1 + k0);
            gload16(Bl + pfo,       Bg0 + k0);
            gload16(Bl + pfo + 512, Bg1 + k0);
        }
        bf16x8 af[4], bfr[4];
        #pragma unroll
        for (int rt = 0; rt < 4; rt++)
            af[rt] = *(const bf16x8*)(smem + curo + (wr * 64 + rt * 16 + l15) * 32 + rch);
        #pragma unroll
        for (int ct = 0; ct < 4; ct++)
            bfr[ct] = *(const bf16x8*)(smem + curo + 4096 + (wc * 64 + ct * 16 + l15) * 32 + rch);
        #pragma unroll
        for (int rt = 0; rt < 4; rt++)
            #pragma unroll
            for (int ct = 0; ct < 4; ct++)
                acc[rt][ct] = mfma16(af[rt], bfr[ct], acc[rt][ct]);
        if (t < 30) {
            asm volatile("s_waitcnt vmcnt(4) lgkmcnt(0)" ::: "memory");
        } else {
            asm volatile("s_waitcnt vmcnt(0) lgkmcnt(0)" ::: "memory");
        }
        __builtin_amdgcn_s_barrier();
        curo += 8192; if (curo == 24576) curo = 0;
        pfo  += 8192; if (pfo  == 24576) pfo  = 0;
    }

    // epilogue: lane holds C[row = wr*64+rt*16+quad*4+i][col = wc*64+ct*16+l15]
    if (!vpath) {
        #pragma unroll
        for (int rt = 0; rt < 4; rt++) {
            #pragma unroll
            for (int i = 0; i < 4; i++) {
                float s = acc[rt][0][i] + acc[rt][1][i] + acc[rt][2][i] + acc[rt][3][i];
                float q = acc[rt][0][i] * acc[rt][0][i] + acc[rt][1][i] * acc[rt][1][i] +
                          acc[rt][2][i] * acc[rt][2][i] + acc[rt][3][i] * acc[rt][3][i];
                #pragma unroll
                for (int off = 1; off < 16; off <<= 1) {
                    s += __shfl_xor(s, off, 64);
                    q += __shfl_xor(q, off, 64);
                }
                float mu = s * (1.f / 64.f);
                float var = q * (1.f / 64.f) - mu * mu;
                float rs = rsqrtf(var + 1e-5f);
                float vals[4];
                #pragma unroll
                for (int ct = 0; ct < 4; ct++) {
                    int hd = ct * 16 + l15;
                    vals[ct] = (acc[rt][ct][i] - mu) * rs * lns[hd] + lnb[hd];
                }
                if (qpath) {  // RoPE pairs (hd, hd+32) = (ct, ct+2), then *0.125*log2e
                    int sp = (m0 + wr * 64 + rt * 16 + quad * 4 + i) & 2047;
                    #pragma unroll
                    for (int ct = 0; ct < 2; ct++) {
                        int hd1 = ct * 16 + l15;
                        float ang = (float)sp * exp2f((float)hd1 * (-13.287712379549449f / 32.f));
                        float sn, cs;
                        sincosf(ang, &sn, &cs);
                        float v1 = vals[ct], v2 = vals[ct + 2];
                        vals[ct]     = v1 * cs - v2 * sn;
                        vals[ct + 2] = v1 * sn + v2 * cs;
                    }
                    #pragma unroll
                    for (int ct = 0; ct < 4; ct++) vals[ct] *= 0.1803368801f;
                }
                #pragma unroll
                for (int ct = 0; ct < 4; ct++) acc[rt][ct][i] = vals[ct];
            }
        }
        drain_barrier();
        short* Csm = smem;  // overlay: [128][132] bf16, +4 pad
        #pragma unroll
        for (int rt = 0; rt < 4; rt++)
            #pragma unroll
            for (int ct = 0; ct < 4; ct++)
                #pragma unroll
                for (int i = 0; i < 4; i++)
                    Csm[(wr * 64 + rt * 16 + quad * 4 + i) * 132 + wc * 64 + ct * 16 + l15] =
                        f2s(acc[rt][ct][i]);
        drain_barrier();
        short* dst = qpath ? outQ : outK;
        #pragma unroll
        for (int it = 0; it < 8; it++) {
            int row = it * 16 + (tid >> 4);
            int chunk = tid & 15;
            bf16x8 v = *(const bf16x8*)(Csm + row * 132 + chunk * 8);
            int hh = ((n0 & 1023) >> 6) + (chunk >> 3);
            int m = m0 + row, b = m >> 11, sp = m & 2047;
            *(bf16x8*)(dst + ((size_t)(b * 16 + hh) * 2048 + sp) * 64 + (chunk & 7) * 8) = v;
        }
    } else {
        // V path: transposed store V^T[b,h,hd,sc]
        const int b = m0 >> 11, h = ((n0 - 1024) >> 6) + wc;
        const int sp = (m0 & 2047) + wr * 64 + quad * 4;
        #pragma unroll
        for (int rt = 0; rt < 4; rt++)
            #pragma unroll
            for (int ct = 0; ct < 4; ct++) {
                short4 pk;
                pk.x = f2s(acc[rt][ct][0]); pk.y = f2s(acc[rt][ct][1]);
                pk.z = f2s(acc[rt][ct][2]); pk.w = f2s(acc[rt][ct][3]);
                int hd = ct * 16 + l15;
                *(short4*)(outV + ((size_t)(b * 16 + h) * 64 + hd) * 2048 + sp + rt * 16) = pk;
            }
    }
}

// ---------------- out-proj GEMM 128x128, K=1024 (R14 mode-2) ----------------
// grid (64,8): x = m-tile (XCD=m%8). 3-buffer counted-vmcnt pipeline.
__global__ __launch_bounds__(256, 3) void gemm_proj(
    const short* __restrict__ A,    // AO [8192][1024]
    const short* __restrict__ Bt,   // WpT [1024][1024]
    float* __restrict__ outF,
    const float* __restrict__ bias_vec) {
    __shared__ short smem[24576];
    const int tid = threadIdx.x;
    const int w = tid >> 6, lane = tid & 63, quad = lane >> 4, l15 = lane & 15;
    const int wr = w & 1, wc = w >> 1;
    const int m0 = blockIdx.x * 128, n0 = blockIdx.y * 128;

    const int srow = lane >> 2, slot = lane & 3;
    const int kslot = (slot ^ ((srow >> 1) & 3)) * 8;
    const short* Ag0 = A + (size_t)(m0 + w * 32 + srow) * 1024 + kslot;
    const short* Ag1 = Ag0 + (size_t)16 * 1024;
    const short* Bg0 = Bt + (size_t)(n0 + w * 32 + srow) * 1024 + kslot;
    const short* Bg1 = Bg0 + (size_t)16 * 1024;
    short* Al = smem + w * 1024;           // + buf*8192
    short* Bl = smem + 4096 + w * 1024;    // + buf*8192

    f32x4 acc[4][4];
    #pragma unroll
    for (int r = 0; r < 4; r++)
        #pragma unroll
        for (int c = 0; c < 4; c++) acc[r][c] = f32x4{0.f, 0.f, 0.f, 0.f};

    const int rsw = (l15 >> 1) & 3;
    const int rch = (quad ^ rsw) * 8;

    gload16(Al,              Ag0);
    gload16(Al + 512,        Ag1);
    gload16(Bl,              Bg0);
    gload16(Bl + 512,        Bg1);
    gload16(Al + 8192,       Ag0 + 32);
    gload16(Al + 8192 + 512, Ag1 + 32);
    gload16(Bl + 8192,       Bg0 + 32);
    gload16(Bl + 8192 + 512, Bg1 + 32);
    asm volatile("s_waitcnt vmcnt(4) lgkmcnt(0)" ::: "memory");
    __builtin_amdgcn_s_barrier();

    int curo = 0;
    int pfo = 16384;
    #pragma unroll 1
    for (int t = 0; t < 32; t++) {
        if (t < 30) {
            const int k0 = (t + 2) * 32;
            gload16(Al + pfo,       Ag0 + k0);
            gload16(Al + pfo + 512, Ag1 + k0);
            gload16(Bl + pfo,       Bg0 + k0);
            gload16(Bl + pfo + 512, Bg1 + k0);
        }
        bf16x8 af[4], bfr[4];
        #pragma unroll
        for (int rt = 0; rt < 4; rt++)
            af[rt] = *(const bf16x8*)(smem + curo + (wr * 64 + rt * 16 + l15) * 32 + rch);
        #pragma unroll
        for (int ct = 0; ct < 4; ct++)
            bfr[ct] = *(const bf16x8*)(smem + curo + 4096 + (wc * 64 + ct * 16 + l15) * 32 + rch);
        #pragma unroll
        for (int rt = 0; rt < 4; rt++)
            #pragma unroll
            for (int ct = 0; ct < 4; ct++)
                acc[rt][ct] = mfma16(af[rt], bfr[ct], acc[rt][ct]);
        if (t < 30) {
            asm volatile("s_waitcnt vmcnt(4) lgkmcnt(0)" ::: "memory");
        } else {
            asm volatile("s_waitcnt vmcnt(0) lgkmcnt(0)" ::: "memory");
        }
        __builtin_amdgcn_s_barrier();
        curo += 8192; if (curo == 24576) curo = 0;
        pfo  += 8192; if (pfo  == 24576) pfo  = 0;
    }

    #pragma unroll
    for (int rt = 0; rt < 4; rt++)
        #pragma unroll
        for (int i = 0; i < 4; i++) {
            size_t m = m0 + wr * 64 + rt * 16 + quad * 4 + i;
            #pragma unroll
            for (int ct = 0; ct < 4; ct++) {
                int n = n0 + wc * 64 + ct * 16 + l15;
                outF[m * 1024 + n] = acc[rt][ct][i] + bias_vec[n];
            }
        }
}

// ---------------- attention: 8-wave blocks (R14/R17 exact, no setprio) ----------------
// S^T = K.Q^T with Q pre-scaled by 0.125*log2e -> p = exp2(st) (row offset
// dropped; cancels in normalization). grid (64,8), 512 threads: block covers
// 256 q-rows (wave w -> rows qt*256 + w*32). Waves 0-3 stage K, 4-7 stage V.
// LDS: K 2buf (16KB) | V 2buf (16KB) | P 8x(32x72) (36KB) = 68KB -> 2 blk/CU.
__global__ __launch_bounds__(512, 4) void attn_kernel(
    const short* __restrict__ Q,   // [64][2048][64]
    const short* __restrict__ K,   // [64][2048][64]
    const short* __restrict__ V,   // [64][64][2048]  (V^T)
    short* __restrict__ AO) {      // [8192][1024] bf16
    __shared__ short smem[8192 + 8192 + 8 * 32 * 72];
    const int tid = threadIdx.x;
    const int w = tid >> 6, lane = tid & 63, quad = lane >> 4, l15 = lane & 15;
    const int bh = blockIdx.x, qt = blockIdx.y;  // grid (64,8): head -> XCD = bh%8
    const short* Qb = Q + (size_t)bh * 2048 * 64;
    const short* Kb = K + (size_t)bh * 2048 * 64;
    const short* Vb = V + (size_t)bh * 64 * 2048;
    short* Pw = smem + 16384 + w * 2304;
    const int q0 = qt * 256 + w * 32;

    // staging role: waves 0-3 stage K tile rows, waves 4-7 stage V^T tile rows
    const int srow = lane >> 2, slot = lane & 3;
    const int sw = (slot ^ ((srow >> 1) & 3)) * 8;
    const int ws = w & 3;
    const bool kstager = (w < 4);
    const short* Sg = kstager ? (Kb + (size_t)(ws * 16 + srow) * 64 + sw)
                              : (Vb + (size_t)(ws * 16 + srow) * 2048 + sw);
    short* Sl0 = smem + (kstager ? 0 : 8192) + ws * 512;
    const int sstep = kstager ? 4096 : 64;  // shorts per kv-tile advance

    bf16x8 bq[2][2];  // [nt][ks]: Q as B-operand B[n=qrow][k=hd]
    #pragma unroll
    for (int nt = 0; nt < 2; nt++)
        #pragma unroll
        for (int ks = 0; ks < 2; ks++)
            bq[nt][ks] = *(const bf16x8*)(Qb + (size_t)(q0 + nt * 16 + l15) * 64 + ks * 32 + quad * 8);

    f32x4 acco[4][2];  // [ct(hd)][nt(qrow)] O^T
    #pragma unroll
    for (int ct = 0; ct < 4; ct++)
        #pragma unroll
        for (int nt = 0; nt < 2; nt++) acco[ct][nt] = f32x4{0.f, 0.f, 0.f, 0.f};
    float lsum[2] = {0.f, 0.f};
    const int rsw = (l15 >> 1) & 3;
    const int rch = (quad ^ rsw) * 8;

    gload16(Sl0,        Sg);
    gload16(Sl0 + 2048, Sg + 32);
    drain_barrier();

    #pragma unroll 1
    for (int t = 0; t < 32; t++) {
        const int cur = (t & 1) * 4096;
        if (t < 31) {
            const int nxt = 4096 - cur;
            gload16(Sl0 + nxt,        Sg + (t + 1) * sstep);
            gload16(Sl0 + nxt + 2048, Sg + (t + 1) * sstep + 32);
        }
        // ---- K fragments, QK^T + exp2 + P stores ----
        bf16x8 ak[4][2];
        #pragma unroll
        for (int mt = 0; mt < 4; mt++)
            #pragma unroll
            for (int ks = 0; ks < 2; ks++)
                ak[mt][ks] = *(const bf16x8*)(smem + cur + ks * 2048 + (mt * 16 + l15) * 32 + rch);

        #pragma unroll
        for (int mt = 0; mt < 4; mt++) {
            #pragma unroll
            for (int nt = 0; nt < 2; nt++) {
                f32x4 st = f32x4{0.f, 0.f, 0.f, 0.f};
                st = mfma16(ak[mt][0], bq[nt][0], st);
                st = mfma16(ak[mt][1], bq[nt][1], st);
                float e0 = __builtin_amdgcn_exp2f(st[0]);
                float e1 = __builtin_amdgcn_exp2f(st[1]);
                float e2 = __builtin_amdgcn_exp2f(st[2]);
                float e3 = __builtin_amdgcn_exp2f(st[3]);
                lsum[nt] += (e0 + e1) + (e2 + e3);
                unsigned int p01 = __builtin_amdgcn_perm(fbits(e1), fbits(e0), 0x07060302u);
                unsigned int p23 = __builtin_amdgcn_perm(fbits(e3), fbits(e2), 0x07060302u);
                uint2 pw;
                pw.x = p01; pw.y = p23;
                *(uint2*)(Pw + (nt * 16 + l15) * 72 + mt * 16 + quad * 4) = pw;
            }
        }
        // P written via uint2*, read via bf16x8*: fence pins program order
        // (wave-local LDS ops execute in issue order -> order == correctness).
        asm volatile("" ::: "memory");

        // ---- V fragments, P reads + PV ----
        bf16x8 av[4][2];
        #pragma unroll
        for (int ct = 0; ct < 4; ct++)
            #pragma unroll
            for (int ks = 0; ks < 2; ks++)
                av[ct][ks] = *(const bf16x8*)(smem + 8192 + cur + ks * 2048 + (ct * 16 + l15) * 32 + rch);

        bf16x8 bp[2][2];
        #pragma unroll
        for (int nt = 0; nt < 2; nt++)
            #pragma unroll
            for (int ks = 0; ks < 2; ks++)
                bp[nt][ks] = *(const bf16x8*)(Pw + (nt * 16 + l15) * 72 + ks * 32 + quad * 8);
        #pragma unroll
        for (int ct = 0; ct < 4; ct++)
            #pragma unroll
            for (int nt = 0; nt < 2; nt++)
                #pragma unroll
                for (int ks = 0; ks < 2; ks++)
                    acco[ct][nt] = mfma16(av[ct][ks], bp[nt][ks], acco[ct][nt]);
        drain_barrier();
    }

    #pragma unroll
    for (int nt = 0; nt < 2; nt++) {
        lsum[nt] += __shfl_xor(lsum[nt], 16, 64);
        lsum[nt] += __shfl_xor(lsum[nt], 32, 64);
    }
    const int b = bh >> 4, h = bh & 15;
    #pragma unroll
    for (int nt = 0; nt < 2; nt++) {
        float inv = 1.f / lsum[nt];
        int sq = q0 + nt * 16 + l15;
        #pragma unroll
        for (int ct = 0; ct < 4; ct++) {
            short4 pk;
            pk.x = f2s(acco[ct][nt][0] * inv); pk.y = f2s(acco[ct][nt][1] * inv);
            pk.z = f2s(acco[ct][nt][2] * inv); pk.w = f2s(acco[ct][nt][3] * inv);
            *(short4*)(AO + ((size_t)b * 2048 + sq) * 1024 + h * 64 + ct * 16 + quad * 4) = pk;
        }
    }
}

extern "C" void kernel_launch(void* const* d_in, const int* in_sizes, int n_in,
                              void* d_out, int out_size, void* d_ws, size_t ws_size,
                              hipStream_t stream) {
    (void)in_sizes; (void)n_in; (void)out_size; (void)ws_size;
    const float* x      = (const float*)d_in[0];
    const float* ctx    = (const float*)d_in[1];
    const float* q_w    = (const float*)d_in[2];
    const float* kv_w   = (const float*)d_in[3];
    const float* qn_s   = (const float*)d_in[4];
    const float* qn_b   = (const float*)d_in[5];
    const float* kn_s   = (const float*)d_in[6];
    const float* kn_b   = (const float*)d_in[7];
    const float* proj_w = (const float*)d_in[8];
    const float* proj_b = (const float*)d_in[9];
    float* out = (float*)d_out;

    char* ws = (char*)d_ws;
    const size_t MB = 1024 * 1024;
    short* xb   = (short*)(ws + 0 * MB);
    short* cb   = (short*)(ws + 16 * MB);
    short* Qb   = (short*)(ws + 32 * MB);   // [64][2048][64] post LN+RoPE+scale
    short* Kb   = (short*)(ws + 48 * MB);   // [64][2048][64] post LN
    short* Vt   = (short*)(ws + 64 * MB);   // [64][64][2048]
    short* AO   = (short*)(ws + 80 * MB);   // [8192][1024]
    short* WqT  = (short*)(ws + 96 * MB);   // 2MB
    short* WkvT = (short*)(ws + 98 * MB);   // 4MB  [2048][1024]
    short* WpT  = (short*)(ws + 102 * MB);  // 2MB

    prep_kernel<<<20480, 256, 0, stream>>>(x, ctx, xb, cb, q_w, kv_w, proj_w, WqT, WkvT, WpT);
    gemm_qkv<<<dim3(64, 24), 256, 0, stream>>>(xb, WqT, cb, WkvT, qn_s, qn_b, kn_s, kn_b,
                                               Qb, Kb, Vt);
    attn_kernel<<<dim3(64, 8), 512, 0, stream>>>(Qb, Kb, Vt, AO);
    gemm_proj<<<dim3(64, 8), 256, 0, stream>>>(AO, WpT, out, proj_b);
}